// Round 1
// baseline (383.554 us; speedup 1.0000x reference)
//
#include <hip/hip_runtime.h>
#include <hip/hip_bf16.h>
#include <stdint.h>

// Problem: MultiheadSelfAttention B=4 S=2048 D=1024 H=16 dh=64, causal, f32 in/out.
// Strategy: bf16 MFMA everywhere. ws layout (shorts):
//   xb[8192*1024] | wq[1M] | wk[1M] | wv[1M] | wo[1M] | Q[64*2048*64] | K[same] | Vt[64*64*2048]
//   attn_out reuses xb (x only needed for the 3 projection GEMMs).

#define S_LEN 2048
#define DM 1024
#define NH 16
#define NB 4
#define DH 64
#define BS (NB * S_LEN)   // 8192 rows

typedef __attribute__((ext_vector_type(4))) float f32x4;
typedef __attribute__((ext_vector_type(8))) short bf16x8;
typedef __attribute__((ext_vector_type(4))) short s16x4;

static __device__ __forceinline__ float bf2f(short u) {
    union { float f; uint32_t i; } c; c.i = ((uint32_t)(uint16_t)u) << 16; return c.f;
}
static __device__ __forceinline__ short f2bf(float f) {
    union { float f; uint32_t i; } c; c.f = f;
    uint32_t r = (c.i + 0x7FFFu + ((c.i >> 16) & 1u)) >> 16;
    return (short)r;
}

// ---------------- cast f32 -> bf16 (vectorized x4) ----------------
__global__ void cast_kernel(const float* __restrict__ in, short* __restrict__ out, int n4) {
    int i = blockIdx.x * blockDim.x + threadIdx.x;
    if (i >= n4) return;
    f32x4 v = *(const f32x4*)(in + (size_t)i * 4);
    s16x4 o;
    o[0] = f2bf(v[0]); o[1] = f2bf(v[1]); o[2] = f2bf(v[2]); o[3] = f2bf(v[3]);
    *(s16x4*)(out + (size_t)i * 4) = o;
}

// ---------------- GEMM: C[M,N] = A[M,K] * B[N,K]^T  (bf16 in, MODE-dependent out) ----
// MODE 0: f32 out, row-major [M,N]
// MODE 1: bf16 out -> [b,h,s,dh]  (row r=b*2048+s, col e=h*64+d)
// MODE 2: bf16 out -> [b,h,dh,s]  (V transposed)
template <int MODE>
__global__ __launch_bounds__(256) void gemm_bt(const short* __restrict__ A,
                                               const short* __restrict__ Bm,
                                               void* __restrict__ Cout,
                                               int M, int N, int Kd) {
    __shared__ __align__(16) short lA[2][128 * 32];
    __shared__ __align__(16) short lB[2][128 * 32];
    const int tid = threadIdx.x;
    const int lane = tid & 63;
    const int wave = tid >> 6;
    const int mb = blockIdx.x;
    const int nb = blockIdx.y;
    const int wm = (wave >> 1) * 64;
    const int wn = (wave & 1) * 64;
    const int c16 = lane & 15;
    const int g = lane >> 4;

    auto stage = [&](int buf, int kb) {
        // each wave stages 1KB per round: rows i*64 + wave*16 + lane/4, cols (lane&3)*8
        for (int i = 0; i < 2; i++) {
            int row = i * 64 + wave * 16 + (lane >> 2);
            int col = (lane & 3) * 8;
            const short* srcA = A + (size_t)(mb * 128 + row) * Kd + kb * 32 + col;
            const short* srcB = Bm + (size_t)(nb * 128 + row) * Kd + kb * 32 + col;
            __builtin_amdgcn_global_load_lds(
                (const __attribute__((address_space(1))) void*)srcA,
                (__attribute__((address_space(3))) void*)(&lA[buf][i * 2048 + wave * 512]),
                16, 0, 0);
            __builtin_amdgcn_global_load_lds(
                (const __attribute__((address_space(1))) void*)srcB,
                (__attribute__((address_space(3))) void*)(&lB[buf][i * 2048 + wave * 512]),
                16, 0, 0);
        }
    };

    f32x4 acc[4][4];
    f32x4 zero = {0.f, 0.f, 0.f, 0.f};
    for (int i = 0; i < 4; i++)
        for (int j = 0; j < 4; j++) acc[i][j] = zero;

    const int nk = Kd >> 5;
    stage(0, 0);
    __syncthreads();
    for (int t = 0; t < nk; t++) {
        int cur = t & 1;
        if (t + 1 < nk) stage(cur ^ 1, t + 1);
        bf16x8 af[4], bfr[4];
        for (int i = 0; i < 4; i++) {
            af[i]  = *(const bf16x8*)&lA[cur][(wm + i * 16 + c16) * 32 + g * 8];
            bfr[i] = *(const bf16x8*)&lB[cur][(wn + i * 16 + c16) * 32 + g * 8];
        }
        for (int mi = 0; mi < 4; mi++)
            for (int ni = 0; ni < 4; ni++)
                acc[mi][ni] = __builtin_amdgcn_mfma_f32_16x16x32_bf16(af[mi], bfr[ni], acc[mi][ni], 0, 0, 0);
        __syncthreads();
    }

    // epilogue: D frag layout col = lane&15, row = (lane>>4)*4 + reg
    for (int mi = 0; mi < 4; mi++) {
        int row0 = mb * 128 + wm + mi * 16 + g * 4;
        for (int ni = 0; ni < 4; ni++) {
            int col = nb * 128 + wn + ni * 16 + c16;
            f32x4 a = acc[mi][ni];
            for (int r = 0; r < 4; r++) {
                int rr = row0 + r;
                if (MODE == 0) {
                    ((float*)Cout)[(size_t)rr * N + col] = a[r];
                } else if (MODE == 1) {
                    int b = rr >> 11, s = rr & 2047, h = col >> 6, d = col & 63;
                    ((short*)Cout)[(((size_t)(b * NH + h) * S_LEN) + s) * DH + d] = f2bf(a[r]);
                } else {
                    int b = rr >> 11, s = rr & 2047, h = col >> 6, d = col & 63;
                    ((short*)Cout)[(((size_t)(b * NH + h) * DH) + d) * S_LEN + s] = f2bf(a[r]);
                }
            }
        }
    }
}

// ---------------- flash attention (causal) -------------------------
// 1 wave = 16 q-rows, independent. Q,K: [bh][s][dh], Vt: [bh][dh][s]. Out: [b,s,D] bf16.
__global__ __launch_bounds__(256) void attn_kernel(const short* __restrict__ Q,
                                                   const short* __restrict__ K,
                                                   const short* __restrict__ Vt,
                                                   short* __restrict__ Oo) {
    __shared__ __align__(16) short plds[4][16 * 32];
    const int lane = threadIdx.x & 63;
    const int wave = threadIdx.x >> 6;
    const int bh = blockIdx.x;             // 0..63
    const int q0 = blockIdx.y * 64 + wave * 16;
    const int b = bh >> 4, h = bh & 15;
    const int c16 = lane & 15;
    const int g = lane >> 4;

    const short* Qb = Q + (size_t)bh * S_LEN * DH;
    const short* Kb = K + (size_t)bh * S_LEN * DH;
    const short* Vb = Vt + (size_t)bh * DH * S_LEN;

    // Q frags, pre-scaled by 1/8 (exact in bf16)
    bf16x8 qf[2];
    {
        int qr = q0 + c16;
        for (int cc = 0; cc < 2; cc++) {
            bf16x8 t = *(const bf16x8*)(Qb + (size_t)qr * DH + cc * 32 + g * 8);
            for (int j = 0; j < 8; j++) t[j] = f2bf(bf2f(t[j]) * 0.125f);
            qf[cc] = t;
        }
    }

    f32x4 zero = {0.f, 0.f, 0.f, 0.f};
    f32x4 o_acc[4];
    for (int i = 0; i < 4; i++) o_acc[i] = zero;
    float m_r[4] = {-1e30f, -1e30f, -1e30f, -1e30f};
    float l_r[4] = {0.f, 0.f, 0.f, 0.f};

    const int kb_end = ((q0 + 15) >> 5) + 1;
    for (int kb = 0; kb < kb_end; kb++) {
        const int kbase = kb * 32;
        // QK^T: scores 16x32 (2 n-tiles of 16 keys)
        f32x4 s[2];
        for (int nt = 0; nt < 2; nt++) {
            bf16x8 kf0 = *(const bf16x8*)(Kb + (size_t)(kbase + nt * 16 + c16) * DH + 0 + g * 8);
            bf16x8 kf1 = *(const bf16x8*)(Kb + (size_t)(kbase + nt * 16 + c16) * DH + 32 + g * 8);
            f32x4 a = zero;
            a = __builtin_amdgcn_mfma_f32_16x16x32_bf16(qf[0], kf0, a, 0, 0, 0);
            a = __builtin_amdgcn_mfma_f32_16x16x32_bf16(qf[1], kf1, a, 0, 0, 0);
            s[nt] = a;
        }
        // mask (only needed near the diagonal)
        float sv[2][4];
        const bool need_mask = (kbase + 31 > q0);
        for (int nt = 0; nt < 2; nt++)
            for (int r = 0; r < 4; r++) {
                float v = s[nt][r];
                if (need_mask) {
                    int kg = kbase + nt * 16 + c16;
                    int qg = q0 + g * 4 + r;
                    if (kg > qg) v = -1e30f;
                }
                sv[nt][r] = v;
            }
        // row max over 32 keys (16-lane groups hold the key axis)
        float alpha[4];
        for (int r = 0; r < 4; r++) {
            float v = fmaxf(sv[0][r], sv[1][r]);
            v = fmaxf(v, __shfl_xor(v, 1));
            v = fmaxf(v, __shfl_xor(v, 2));
            v = fmaxf(v, __shfl_xor(v, 4));
            v = fmaxf(v, __shfl_xor(v, 8));
            float mn = fmaxf(m_r[r], v);
            alpha[r] = __expf(m_r[r] - mn);
            m_r[r] = mn;
        }
        // P = exp(s - m), write to per-wave LDS tile (D-layout -> A-layout)
        for (int r = 0; r < 4; r++) {
            float p0 = __expf(sv[0][r] - m_r[r]);
            float p1 = __expf(sv[1][r] - m_r[r]);
            plds[wave][(g * 4 + r) * 32 + c16] = f2bf(p0);
            plds[wave][(g * 4 + r) * 32 + 16 + c16] = f2bf(p1);
            float t = p0 + p1;
            t += __shfl_xor(t, 1);
            t += __shfl_xor(t, 2);
            t += __shfl_xor(t, 4);
            t += __shfl_xor(t, 8);
            l_r[r] = l_r[r] * alpha[r] + t;
        }
        // rescale O
        for (int d4 = 0; d4 < 4; d4++) {
            f32x4 o = o_acc[d4];
            for (int r = 0; r < 4; r++) o[r] *= alpha[r];
            o_acc[d4] = o;
        }
        // PV: A-frag from LDS (row c16, k = g*8..+7), B-frag from Vt rows (dh), contiguous keys
        bf16x8 pa = *(const bf16x8*)&plds[wave][c16 * 32 + g * 8];
        for (int d4 = 0; d4 < 4; d4++) {
            bf16x8 vf = *(const bf16x8*)(Vb + (size_t)(d4 * 16 + c16) * S_LEN + kbase + g * 8);
            o_acc[d4] = __builtin_amdgcn_mfma_f32_16x16x32_bf16(pa, vf, o_acc[d4], 0, 0, 0);
        }
    }

    // write attn_out [b, s, D] bf16
    for (int r = 0; r < 4; r++) {
        float inv = 1.0f / l_r[r];
        int qg = q0 + g * 4 + r;
        size_t rowoff = ((size_t)b * S_LEN + qg) * DM + h * DH;
        for (int d4 = 0; d4 < 4; d4++)
            Oo[rowoff + d4 * 16 + c16] = f2bf(o_acc[d4][r] * inv);
    }
}

extern "C" void kernel_launch(void* const* d_in, const int* in_sizes, int n_in,
                              void* d_out, int out_size, void* d_ws, size_t ws_size,
                              hipStream_t stream) {
    const float* x  = (const float*)d_in[0];
    const float* wq = (const float*)d_in[1];
    const float* wk = (const float*)d_in[2];
    const float* wv = (const float*)d_in[3];
    const float* wo = (const float*)d_in[4];
    float* out = (float*)d_out;

    short* ws = (short*)d_ws;
    size_t off = 0;
    short* xb  = ws + off; off += (size_t)BS * DM;       // 8.4M
    short* wqb = ws + off; off += (size_t)DM * DM;
    short* wkb = ws + off; off += (size_t)DM * DM;
    short* wvb = ws + off; off += (size_t)DM * DM;
    short* wob = ws + off; off += (size_t)DM * DM;
    short* Qb  = ws + off; off += (size_t)BS * DM;
    short* Kb  = ws + off; off += (size_t)BS * DM;
    short* Vtb = ws + off; off += (size_t)BS * DM;
    short* attn_o = xb;  // reuse: x dead after projections

    // casts
    {
        int n4 = (BS * DM) / 4;
        cast_kernel<<<n4 / 256, 256, 0, stream>>>(x, xb, n4);
        int w4 = (DM * DM) / 4;
        cast_kernel<<<w4 / 256, 256, 0, stream>>>(wq, wqb, w4);
        cast_kernel<<<w4 / 256, 256, 0, stream>>>(wk, wkb, w4);
        cast_kernel<<<w4 / 256, 256, 0, stream>>>(wv, wvb, w4);
        cast_kernel<<<w4 / 256, 256, 0, stream>>>(wo, wob, w4);
    }

    dim3 pgrid(BS / 128, DM / 128);
    gemm_bt<1><<<pgrid, 256, 0, stream>>>(xb, wqb, Qb,  BS, DM, DM);
    gemm_bt<1><<<pgrid, 256, 0, stream>>>(xb, wkb, Kb,  BS, DM, DM);
    gemm_bt<2><<<pgrid, 256, 0, stream>>>(xb, wvb, Vtb, BS, DM, DM);

    attn_kernel<<<dim3(NB * NH, S_LEN / 64), 256, 0, stream>>>(Qb, Kb, Vtb, attn_o);

    gemm_bt<0><<<pgrid, 256, 0, stream>>>(attn_o, wob, out, BS, DM, DM);
}

// Round 2
// 319.112 us; speedup vs baseline: 1.2019x; 1.2019x over previous
//
#include <hip/hip_runtime.h>
#include <hip/hip_bf16.h>
#include <stdint.h>

// MultiheadSelfAttention B=4 S=2048 D=1024 H=16 dh=64, causal, f32 in/out.
// bf16 MFMA everywhere. ws layout (shorts):
//   xb[8192*1024] | wq[1M] | wk[1M] | wv[1M] | wo[1M] | Q | K | Vt
//   attn_out reuses xb.
// R2: attention rewritten to swapped-QK 32x32x16 structure (in-register softmax,
//     no LDS, O^T accumulation so alpha-rescale is per-lane scalar).

#define S_LEN 2048
#define DM 1024
#define NH 16
#define NB 4
#define DH 64
#define BS (NB * S_LEN)   // 8192 rows

typedef __attribute__((ext_vector_type(4))) float f32x4;
typedef __attribute__((ext_vector_type(16))) float f32x16;
typedef __attribute__((ext_vector_type(8))) short bf16x8;
typedef __attribute__((ext_vector_type(4))) short s16x4;

static __device__ __forceinline__ float bf2f(short u) {
    union { float f; uint32_t i; } c; c.i = ((uint32_t)(uint16_t)u) << 16; return c.f;
}
static __device__ __forceinline__ short f2bf(float f) {
    union { float f; uint32_t i; } c; c.f = f;
    uint32_t r = (c.i + 0x7FFFu + ((c.i >> 16) & 1u)) >> 16;
    return (short)r;
}

// ---------------- cast f32 -> bf16 (vectorized x4) ----------------
__global__ void cast_kernel(const float* __restrict__ in, short* __restrict__ out, int n4) {
    int i = blockIdx.x * blockDim.x + threadIdx.x;
    if (i >= n4) return;
    f32x4 v = *(const f32x4*)(in + (size_t)i * 4);
    s16x4 o;
    o[0] = f2bf(v[0]); o[1] = f2bf(v[1]); o[2] = f2bf(v[2]); o[3] = f2bf(v[3]);
    *(s16x4*)(out + (size_t)i * 4) = o;
}

// ---------------- GEMM: C[M,N] = A[M,K] * B[N,K]^T  (bf16 in) ----
// MODE 0: f32 out, row-major [M,N]
// MODE 1: bf16 out -> [b,h,s,dh]
// MODE 2: bf16 out -> [b,h,dh,s]  (V transposed)
template <int MODE>
__global__ __launch_bounds__(256) void gemm_bt(const short* __restrict__ A,
                                               const short* __restrict__ Bm,
                                               void* __restrict__ Cout,
                                               int M, int N, int Kd) {
    __shared__ __align__(16) short lA[2][128 * 32];
    __shared__ __align__(16) short lB[2][128 * 32];
    const int tid = threadIdx.x;
    const int lane = tid & 63;
    const int wave = tid >> 6;
    const int mb = blockIdx.x;
    const int nb = blockIdx.y;
    const int wm = (wave >> 1) * 64;
    const int wn = (wave & 1) * 64;
    const int c16 = lane & 15;
    const int g = lane >> 4;

    auto stage = [&](int buf, int kb) {
        for (int i = 0; i < 2; i++) {
            int row = i * 64 + wave * 16 + (lane >> 2);
            int col = (lane & 3) * 8;
            const short* srcA = A + (size_t)(mb * 128 + row) * Kd + kb * 32 + col;
            const short* srcB = Bm + (size_t)(nb * 128 + row) * Kd + kb * 32 + col;
            __builtin_amdgcn_global_load_lds(
                (const __attribute__((address_space(1))) void*)srcA,
                (__attribute__((address_space(3))) void*)(&lA[buf][i * 2048 + wave * 512]),
                16, 0, 0);
            __builtin_amdgcn_global_load_lds(
                (const __attribute__((address_space(1))) void*)srcB,
                (__attribute__((address_space(3))) void*)(&lB[buf][i * 2048 + wave * 512]),
                16, 0, 0);
        }
    };

    f32x4 acc[4][4];
    f32x4 zero = {0.f, 0.f, 0.f, 0.f};
    for (int i = 0; i < 4; i++)
        for (int j = 0; j < 4; j++) acc[i][j] = zero;

    const int nk = Kd >> 5;
    stage(0, 0);
    __syncthreads();
    for (int t = 0; t < nk; t++) {
        int cur = t & 1;
        if (t + 1 < nk) stage(cur ^ 1, t + 1);
        bf16x8 af[4], bfr[4];
        for (int i = 0; i < 4; i++) {
            af[i]  = *(const bf16x8*)&lA[cur][(wm + i * 16 + c16) * 32 + g * 8];
            bfr[i] = *(const bf16x8*)&lB[cur][(wn + i * 16 + c16) * 32 + g * 8];
        }
        for (int mi = 0; mi < 4; mi++)
            for (int ni = 0; ni < 4; ni++)
                acc[mi][ni] = __builtin_amdgcn_mfma_f32_16x16x32_bf16(af[mi], bfr[ni], acc[mi][ni], 0, 0, 0);
        __syncthreads();
    }

    for (int mi = 0; mi < 4; mi++) {
        int row0 = mb * 128 + wm + mi * 16 + g * 4;
        for (int ni = 0; ni < 4; ni++) {
            int col = nb * 128 + wn + ni * 16 + c16;
            f32x4 a = acc[mi][ni];
            for (int r = 0; r < 4; r++) {
                int rr = row0 + r;
                if (MODE == 0) {
                    ((float*)Cout)[(size_t)rr * N + col] = a[r];
                } else if (MODE == 1) {
                    int b = rr >> 11, s = rr & 2047, h = col >> 6, d = col & 63;
                    ((short*)Cout)[(((size_t)(b * NH + h) * S_LEN) + s) * DH + d] = f2bf(a[r]);
                } else {
                    int b = rr >> 11, s = rr & 2047, h = col >> 6, d = col & 63;
                    ((short*)Cout)[(((size_t)(b * NH + h) * DH) + d) * S_LEN + s] = f2bf(a[r]);
                }
            }
        }
    }
}

// ---------------- flash attention, swapped-QK 32x32x16, causal ------------
// 1 wave = 32 q-rows of one (b,h). ST = mfma(K,Q): lane holds 16 scores of
// q = q0+(lane&31) at k_local = (r&3)+8*(r>>2)+4*hi. Softmax in-register
// (1 shfl_xor(32) per reduce). P packed to bf16 via v_perm, word-exchange via
// shfl_xor(32). PV computes O^T = mfma(Vt_frag, P_frag) -> alpha rescale is
// per-lane scalar. Out: [b,s,D] bf16.
__global__ __launch_bounds__(256) void attn32_kernel(const short* __restrict__ Q,
                                                     const short* __restrict__ K,
                                                     const short* __restrict__ Vt,
                                                     short* __restrict__ Oo) {
    const int lane = threadIdx.x & 63;
    const int wave = threadIdx.x >> 6;
    const int item = blockIdx.x * 4 + wave;     // 4096 items
    const int bh = item & 63;
    const int idx = item >> 6;                  // 0..63
    const int qt = (idx & 1) ? (63 - (idx >> 1)) : (idx >> 1);  // balance
    const int q0 = qt * 32;
    const int b = bh >> 4, h = bh & 15;
    const int l31 = lane & 31;
    const int hi = lane >> 5;
    const int qrow = q0 + l31;

    const short* Qb = Q + (size_t)bh * S_LEN * DH;
    const short* Kb = K + (size_t)bh * S_LEN * DH;
    const short* Vb = Vt + (size_t)bh * DH * S_LEN;

    // Q fragments (B-operand layout: n=q=lane&31, k = c*16 + hi*8 + j), prescaled 1/8
    bf16x8 qf[4];
    for (int c = 0; c < 4; c++) {
        bf16x8 t = *(const bf16x8*)(Qb + (size_t)qrow * DH + c * 16 + hi * 8);
        for (int j = 0; j < 8; j++) t[j] = f2bf(bf2f(t[j]) * 0.125f);
        qf[c] = t;
    }

    f32x16 o0, o1;
    for (int r = 0; r < 16; r++) { o0[r] = 0.f; o1[r] = 0.f; }
    float m_r = -1e30f, l_r = 0.f;

    const int nkt = qt + 1;
    for (int kb = 0; kb < nkt; kb++) {
        const int kbase = kb * 32;
        // QK^T swapped: ST[k][q], 4 dh-chunks of K=16
        f32x16 st;
        for (int r = 0; r < 16; r++) st[r] = 0.f;
        for (int c = 0; c < 4; c++) {
            bf16x8 kf = *(const bf16x8*)(Kb + (size_t)(kbase + l31) * DH + c * 16 + hi * 8);
            st = __builtin_amdgcn_mfma_f32_32x32x16_bf16(kf, qf[c], st, 0, 0, 0);
        }
        float p[16];
        if (kb == nkt - 1) {
            #pragma unroll
            for (int r = 0; r < 16; r++) {
                int kl = (r & 3) + 8 * (r >> 2) + 4 * hi;
                p[r] = (kbase + kl > qrow) ? -1e30f : st[r];
            }
        } else {
            #pragma unroll
            for (int r = 0; r < 16; r++) p[r] = st[r];
        }
        // row max (16 in-lane + cross-half)
        float mx = fmaxf(fmaxf(fmaxf(p[0], p[1]), fmaxf(p[2], p[3])),
                         fmaxf(fmaxf(p[4], p[5]), fmaxf(p[6], p[7])));
        float mx2 = fmaxf(fmaxf(fmaxf(p[8], p[9]), fmaxf(p[10], p[11])),
                          fmaxf(fmaxf(p[12], p[13]), fmaxf(p[14], p[15])));
        mx = fmaxf(mx, mx2);
        mx = fmaxf(mx, __shfl_xor(mx, 32));
        float mn = fmaxf(m_r, mx);
        float alpha = __expf(m_r - mn);
        m_r = mn;
        float sum = 0.f;
        #pragma unroll
        for (int r = 0; r < 16; r++) { p[r] = __expf(p[r] - mn); sum += p[r]; }
        sum += __shfl_xor(sum, 32);
        l_r = l_r * alpha + sum;
        #pragma unroll
        for (int r = 0; r < 16; r++) { o0[r] *= alpha; o1[r] *= alpha; }

        // pack P pairs to bf16 words (RN via +0x8000 then byte-perm)
        uint32_t w[8], x[8];
        #pragma unroll
        for (int i = 0; i < 8; i++) {
            union { float f; uint32_t u; } a0, a1;
            a0.f = p[2 * i]; a1.f = p[2 * i + 1];
            w[i] = __builtin_amdgcn_perm(a1.u + 0x8000u, a0.u + 0x8000u, 0x07060302u);
        }
        #pragma unroll
        for (int i = 0; i < 8; i++) x[i] = (uint32_t)__shfl_xor((int)w[i], 32);
        // assemble B-operand frags (n=q, k = kc*16 + hi*8 + j)
        uint32_t pb0[4], pb1[4];
        pb0[0] = hi ? x[2] : w[0]; pb0[1] = hi ? x[3] : w[1];
        pb0[2] = hi ? w[2] : x[0]; pb0[3] = hi ? w[3] : x[1];
        pb1[0] = hi ? x[6] : w[4]; pb1[1] = hi ? x[7] : w[5];
        pb1[2] = hi ? w[6] : x[4]; pb1[3] = hi ? w[7] : x[5];
        union { uint32_t u[4]; bf16x8 v; } c0, c1;
        for (int i = 0; i < 4; i++) { c0.u[i] = pb0[i]; c1.u[i] = pb1[i]; }

        // PV: O^T[d][q] += V^T-frag x P-frag  (A: m=d=lane&31, k = kc*16+hi*8+j)
        bf16x8 v00 = *(const bf16x8*)(Vb + (size_t)(0 + l31) * S_LEN + kbase + hi * 8);
        bf16x8 v01 = *(const bf16x8*)(Vb + (size_t)(0 + l31) * S_LEN + kbase + 16 + hi * 8);
        bf16x8 v10 = *(const bf16x8*)(Vb + (size_t)(32 + l31) * S_LEN + kbase + hi * 8);
        bf16x8 v11 = *(const bf16x8*)(Vb + (size_t)(32 + l31) * S_LEN + kbase + 16 + hi * 8);
        o0 = __builtin_amdgcn_mfma_f32_32x32x16_bf16(v00, c0.v, o0, 0, 0, 0);
        o0 = __builtin_amdgcn_mfma_f32_32x32x16_bf16(v01, c1.v, o0, 0, 0, 0);
        o1 = __builtin_amdgcn_mfma_f32_32x32x16_bf16(v10, c0.v, o1, 0, 0, 0);
        o1 = __builtin_amdgcn_mfma_f32_32x32x16_bf16(v11, c1.v, o1, 0, 0, 0);
    }

    // epilogue: O^T lane holds q=qrow, d = dc*32 + (r&3)+8*(r>>2)+4*hi
    float inv = 1.0f / l_r;
    size_t base = ((size_t)b * S_LEN + qrow) * DM + h * DH;
    #pragma unroll
    for (int g2 = 0; g2 < 4; g2++) {
        s16x4 a, c;
        #pragma unroll
        for (int rr = 0; rr < 4; rr++) a[rr] = f2bf(o0[g2 * 4 + rr] * inv);
        *(s16x4*)(Oo + base + 0 + g2 * 8 + hi * 4) = a;
        #pragma unroll
        for (int rr = 0; rr < 4; rr++) c[rr] = f2bf(o1[g2 * 4 + rr] * inv);
        *(s16x4*)(Oo + base + 32 + g2 * 8 + hi * 4) = c;
    }
}

extern "C" void kernel_launch(void* const* d_in, const int* in_sizes, int n_in,
                              void* d_out, int out_size, void* d_ws, size_t ws_size,
                              hipStream_t stream) {
    const float* x  = (const float*)d_in[0];
    const float* wq = (const float*)d_in[1];
    const float* wk = (const float*)d_in[2];
    const float* wv = (const float*)d_in[3];
    const float* wo = (const float*)d_in[4];
    float* out = (float*)d_out;

    short* ws = (short*)d_ws;
    size_t off = 0;
    short* xb  = ws + off; off += (size_t)BS * DM;
    short* wqb = ws + off; off += (size_t)DM * DM;
    short* wkb = ws + off; off += (size_t)DM * DM;
    short* wvb = ws + off; off += (size_t)DM * DM;
    short* wob = ws + off; off += (size_t)DM * DM;
    short* Qb  = ws + off; off += (size_t)BS * DM;
    short* Kb  = ws + off; off += (size_t)BS * DM;
    short* Vtb = ws + off; off += (size_t)BS * DM;
    short* attn_o = xb;  // reuse: x dead after projections

    {
        int n4 = (BS * DM) / 4;
        cast_kernel<<<n4 / 256, 256, 0, stream>>>(x, xb, n4);
        int w4 = (DM * DM) / 4;
        cast_kernel<<<w4 / 256, 256, 0, stream>>>(wq, wqb, w4);
        cast_kernel<<<w4 / 256, 256, 0, stream>>>(wk, wkb, w4);
        cast_kernel<<<w4 / 256, 256, 0, stream>>>(wv, wvb, w4);
        cast_kernel<<<w4 / 256, 256, 0, stream>>>(wo, wob, w4);
    }

    dim3 pgrid(BS / 128, DM / 128);
    gemm_bt<1><<<pgrid, 256, 0, stream>>>(xb, wqb, Qb,  BS, DM, DM);
    gemm_bt<1><<<pgrid, 256, 0, stream>>>(xb, wkb, Kb,  BS, DM, DM);
    gemm_bt<2><<<pgrid, 256, 0, stream>>>(xb, wvb, Vtb, BS, DM, DM);

    attn32_kernel<<<dim3(4096 / 4), 256, 0, stream>>>(Qb, Kb, Vtb, attn_o);

    gemm_bt<0><<<pgrid, 256, 0, stream>>>(attn_o, wob, out, BS, DM, DM);
}

// Round 3
// 251.849 us; speedup vs baseline: 1.5230x; 1.2671x over previous
//
#include <hip/hip_runtime.h>
#include <hip/hip_bf16.h>
#include <stdint.h>

// MultiheadSelfAttention B=4 S=2048 D=1024 H=16 dh=64, causal, f32 in/out.
// R3: attention = swapped-QK 32x32x16, 2-wave in-block split-K with LDS merge,
//     long/short qt pairing per block, register-rotating K/V prefetch, setprio.

#define S_LEN 2048
#define DM 1024
#define NH 16
#define NB 4
#define DH 64
#define BS (NB * S_LEN)   // 8192 rows

typedef __attribute__((ext_vector_type(4))) float f32x4;
typedef __attribute__((ext_vector_type(16))) float f32x16;
typedef __attribute__((ext_vector_type(8))) short bf16x8;
typedef __attribute__((ext_vector_type(4))) short s16x4;

static __device__ __forceinline__ float bf2f(short u) {
    union { float f; uint32_t i; } c; c.i = ((uint32_t)(uint16_t)u) << 16; return c.f;
}
static __device__ __forceinline__ short f2bf(float f) {
    union { float f; uint32_t i; } c; c.f = f;
    uint32_t r = (c.i + 0x7FFFu + ((c.i >> 16) & 1u)) >> 16;
    return (short)r;
}

// ---------------- cast f32 -> bf16 (vectorized x4) ----------------
__global__ void cast_kernel(const float* __restrict__ in, short* __restrict__ out, int n4) {
    int i = blockIdx.x * blockDim.x + threadIdx.x;
    if (i >= n4) return;
    f32x4 v = *(const f32x4*)(in + (size_t)i * 4);
    s16x4 o;
    o[0] = f2bf(v[0]); o[1] = f2bf(v[1]); o[2] = f2bf(v[2]); o[3] = f2bf(v[3]);
    *(s16x4*)(out + (size_t)i * 4) = o;
}

// ---------------- GEMM: C[M,N] = A[M,K] * B[N,K]^T  (bf16 in) ----
// MODE 0: f32 out row-major; MODE 1: bf16 -> [b,h,s,dh]; MODE 2: bf16 -> [b,h,dh,s]
template <int MODE>
__global__ __launch_bounds__(256) void gemm_bt(const short* __restrict__ A,
                                               const short* __restrict__ Bm,
                                               void* __restrict__ Cout,
                                               int M, int N, int Kd) {
    __shared__ __align__(16) short lA[2][128 * 32];
    __shared__ __align__(16) short lB[2][128 * 32];
    const int tid = threadIdx.x;
    const int lane = tid & 63;
    const int wave = tid >> 6;
    const int mb = blockIdx.x;
    const int nb = blockIdx.y;
    const int wm = (wave >> 1) * 64;
    const int wn = (wave & 1) * 64;
    const int c16 = lane & 15;
    const int g = lane >> 4;

    auto stage = [&](int buf, int kb) {
        for (int i = 0; i < 2; i++) {
            int row = i * 64 + wave * 16 + (lane >> 2);
            int col = (lane & 3) * 8;
            const short* srcA = A + (size_t)(mb * 128 + row) * Kd + kb * 32 + col;
            const short* srcB = Bm + (size_t)(nb * 128 + row) * Kd + kb * 32 + col;
            __builtin_amdgcn_global_load_lds(
                (const __attribute__((address_space(1))) void*)srcA,
                (__attribute__((address_space(3))) void*)(&lA[buf][i * 2048 + wave * 512]),
                16, 0, 0);
            __builtin_amdgcn_global_load_lds(
                (const __attribute__((address_space(1))) void*)srcB,
                (__attribute__((address_space(3))) void*)(&lB[buf][i * 2048 + wave * 512]),
                16, 0, 0);
        }
    };

    f32x4 acc[4][4];
    f32x4 zero = {0.f, 0.f, 0.f, 0.f};
    for (int i = 0; i < 4; i++)
        for (int j = 0; j < 4; j++) acc[i][j] = zero;

    const int nk = Kd >> 5;
    stage(0, 0);
    __syncthreads();
    for (int t = 0; t < nk; t++) {
        int cur = t & 1;
        if (t + 1 < nk) stage(cur ^ 1, t + 1);
        bf16x8 af[4], bfr[4];
        for (int i = 0; i < 4; i++) {
            af[i]  = *(const bf16x8*)&lA[cur][(wm + i * 16 + c16) * 32 + g * 8];
            bfr[i] = *(const bf16x8*)&lB[cur][(wn + i * 16 + c16) * 32 + g * 8];
        }
        for (int mi = 0; mi < 4; mi++)
            for (int ni = 0; ni < 4; ni++)
                acc[mi][ni] = __builtin_amdgcn_mfma_f32_16x16x32_bf16(af[mi], bfr[ni], acc[mi][ni], 0, 0, 0);
        __syncthreads();
    }

    for (int mi = 0; mi < 4; mi++) {
        int row0 = mb * 128 + wm + mi * 16 + g * 4;
        for (int ni = 0; ni < 4; ni++) {
            int col = nb * 128 + wn + ni * 16 + c16;
            f32x4 a = acc[mi][ni];
            for (int r = 0; r < 4; r++) {
                int rr = row0 + r;
                if (MODE == 0) {
                    ((float*)Cout)[(size_t)rr * N + col] = a[r];
                } else if (MODE == 1) {
                    int b = rr >> 11, s = rr & 2047, h = col >> 6, d = col & 63;
                    ((short*)Cout)[(((size_t)(b * NH + h) * S_LEN) + s) * DH + d] = f2bf(a[r]);
                } else {
                    int b = rr >> 11, s = rr & 2047, h = col >> 6, d = col & 63;
                    ((short*)Cout)[(((size_t)(b * NH + h) * DH) + d) * S_LEN + s] = f2bf(a[r]);
                }
            }
        }
    }
}

// ---------------- flash attention, 2-wave split-K + LDS merge ------------
// Block = 256 thr = 4 waves = 2 items: item0 = (bh, 63-j) long, item1 = (bh, j).
// Each item's k-range split across 2 waves; partials merged via LDS.
// ST = mfma(K,Q) swapped: lane holds 16 scores of q=q0+(lane&31) at
// k_local = (r&3)+8*(r>>2)+4*hi. O^T = mfma(Vt,P): alpha rescale per-lane.
__global__ __launch_bounds__(256, 4) void attn_split_kernel(const short* __restrict__ Q,
                                                            const short* __restrict__ K,
                                                            const short* __restrict__ Vt,
                                                            short* __restrict__ Oo) {
    __shared__ __align__(16) float lO[2][32][68];   // [item][q][d] (+4 pad)
    __shared__ float lML[2][2][32];
    const int lane = threadIdx.x & 63;
    const int wave = threadIdx.x >> 6;
    const int item = wave >> 1;
    const int half = wave & 1;
    const int j = blockIdx.x >> 6;        // 0..31
    const int bh = blockIdx.x & 63;
    const int qt = item ? j : (63 - j);
    const int q0 = qt * 32;
    const int b = bh >> 4, h = bh & 15;
    const int l31 = lane & 31;
    const int hi = lane >> 5;
    const int qrow = q0 + l31;
    const int nk = qt + 1;
    const int hh = (nk + 1) >> 1;
    const int t0 = half ? hh : 0;
    const int t1 = half ? nk : hh;

    const short* Qb = Q + (size_t)bh * S_LEN * DH;
    const short* Kb = K + (size_t)bh * S_LEN * DH;
    const short* Vb = Vt + (size_t)bh * DH * S_LEN;

    // Q fragments (B-operand: n=q=lane&31, k = c*16 + hi*8 + jj), prescaled 1/8
    bf16x8 qf[4];
    #pragma unroll
    for (int c = 0; c < 4; c++) {
        bf16x8 t = *(const bf16x8*)(Qb + (size_t)qrow * DH + c * 16 + hi * 8);
        #pragma unroll
        for (int jj = 0; jj < 8; jj++) t[jj] = f2bf(bf2f(t[jj]) * 0.125f);
        qf[c] = t;
    }

    f32x16 o0, o1;
    #pragma unroll
    for (int r = 0; r < 16; r++) { o0[r] = 0.f; o1[r] = 0.f; }
    float m_r = -1e30f, l_r = 0.f;

    bf16x8 kf[4], vf[4];
    if (t0 < t1) {
        const short* kp = Kb + (size_t)(t0 * 32 + l31) * DH + hi * 8;
        kf[0] = *(const bf16x8*)(kp);
        kf[1] = *(const bf16x8*)(kp + 16);
        kf[2] = *(const bf16x8*)(kp + 32);
        kf[3] = *(const bf16x8*)(kp + 48);
        const short* vp = Vb + (size_t)l31 * S_LEN + t0 * 32 + hi * 8;
        vf[0] = *(const bf16x8*)(vp);
        vf[1] = *(const bf16x8*)(vp + 16);
        vf[2] = *(const bf16x8*)(vp + (size_t)32 * S_LEN);
        vf[3] = *(const bf16x8*)(vp + (size_t)32 * S_LEN + 16);
    }

    for (int kb = t0; kb < t1; kb++) {
        const int kbase = kb * 32;
        f32x16 st;
        #pragma unroll
        for (int r = 0; r < 16; r++) st[r] = 0.f;
        __builtin_amdgcn_s_setprio(1);
        st = __builtin_amdgcn_mfma_f32_32x32x16_bf16(kf[0], qf[0], st, 0, 0, 0);
        st = __builtin_amdgcn_mfma_f32_32x32x16_bf16(kf[1], qf[1], st, 0, 0, 0);
        st = __builtin_amdgcn_mfma_f32_32x32x16_bf16(kf[2], qf[2], st, 0, 0, 0);
        st = __builtin_amdgcn_mfma_f32_32x32x16_bf16(kf[3], qf[3], st, 0, 0, 0);
        __builtin_amdgcn_s_setprio(0);
        if (kb + 1 < t1) {  // rotate-prefetch K for next tile (same regs)
            const short* kp = Kb + (size_t)((kb + 1) * 32 + l31) * DH + hi * 8;
            kf[0] = *(const bf16x8*)(kp);
            kf[1] = *(const bf16x8*)(kp + 16);
            kf[2] = *(const bf16x8*)(kp + 32);
            kf[3] = *(const bf16x8*)(kp + 48);
        }
        float p[16];
        if (kbase + 31 > q0) {      // diagonal tile: apply causal mask
            #pragma unroll
            for (int r = 0; r < 16; r++) {
                int kl = (r & 3) + 8 * (r >> 2) + 4 * hi;
                p[r] = (kbase + kl > qrow) ? -1e30f : st[r];
            }
        } else {
            #pragma unroll
            for (int r = 0; r < 16; r++) p[r] = st[r];
        }
        // row max
        float mx = fmaxf(fmaxf(fmaxf(p[0], p[1]), fmaxf(p[2], p[3])),
                         fmaxf(fmaxf(p[4], p[5]), fmaxf(p[6], p[7])));
        float mx2 = fmaxf(fmaxf(fmaxf(p[8], p[9]), fmaxf(p[10], p[11])),
                          fmaxf(fmaxf(p[12], p[13]), fmaxf(p[14], p[15])));
        mx = fmaxf(mx, mx2);
        mx = fmaxf(mx, __shfl_xor(mx, 32));
        float mn = fmaxf(m_r, mx);
        float alpha = __expf(m_r - mn);
        m_r = mn;
        float sum = 0.f;
        #pragma unroll
        for (int r = 0; r < 16; r++) { p[r] = __expf(p[r] - mn); sum += p[r]; }
        sum += __shfl_xor(sum, 32);
        l_r = l_r * alpha + sum;
        #pragma unroll
        for (int r = 0; r < 16; r++) { o0[r] *= alpha; o1[r] *= alpha; }

        // pack P pairs to bf16 words, exchange halves
        uint32_t w[8], x[8];
        #pragma unroll
        for (int i = 0; i < 8; i++) {
            union { float f; uint32_t u; } a0, a1;
            a0.f = p[2 * i]; a1.f = p[2 * i + 1];
            w[i] = __builtin_amdgcn_perm(a1.u + 0x8000u, a0.u + 0x8000u, 0x07060302u);
        }
        #pragma unroll
        for (int i = 0; i < 8; i++) x[i] = (uint32_t)__shfl_xor((int)w[i], 32);
        uint32_t pb0[4], pb1[4];
        pb0[0] = hi ? x[2] : w[0]; pb0[1] = hi ? x[3] : w[1];
        pb0[2] = hi ? w[2] : x[0]; pb0[3] = hi ? w[3] : x[1];
        pb1[0] = hi ? x[6] : w[4]; pb1[1] = hi ? x[7] : w[5];
        pb1[2] = hi ? w[6] : x[4]; pb1[3] = hi ? w[7] : x[5];
        union { uint32_t u[4]; bf16x8 v; } c0, c1;
        #pragma unroll
        for (int i = 0; i < 4; i++) { c0.u[i] = pb0[i]; c1.u[i] = pb1[i]; }

        __builtin_amdgcn_s_setprio(1);
        o0 = __builtin_amdgcn_mfma_f32_32x32x16_bf16(vf[0], c0.v, o0, 0, 0, 0);
        o0 = __builtin_amdgcn_mfma_f32_32x32x16_bf16(vf[1], c1.v, o0, 0, 0, 0);
        o1 = __builtin_amdgcn_mfma_f32_32x32x16_bf16(vf[2], c0.v, o1, 0, 0, 0);
        o1 = __builtin_amdgcn_mfma_f32_32x32x16_bf16(vf[3], c1.v, o1, 0, 0, 0);
        __builtin_amdgcn_s_setprio(0);
        if (kb + 1 < t1) {  // rotate-prefetch V for next tile
            const short* vp = Vb + (size_t)l31 * S_LEN + (kb + 1) * 32 + hi * 8;
            vf[0] = *(const bf16x8*)(vp);
            vf[1] = *(const bf16x8*)(vp + 16);
            vf[2] = *(const bf16x8*)(vp + (size_t)32 * S_LEN);
            vf[3] = *(const bf16x8*)(vp + (size_t)32 * S_LEN + 16);
        }
    }

    // ---- merge the two halves via LDS ----
    if (half == 0) {
        #pragma unroll
        for (int dc = 0; dc < 2; dc++)
            #pragma unroll
            for (int g2 = 0; g2 < 4; g2++) {
                f32x4 w4;
                #pragma unroll
                for (int rr = 0; rr < 4; rr++) w4[rr] = (dc ? o1 : o0)[g2 * 4 + rr];
                *(f32x4*)&lO[item][l31][dc * 32 + g2 * 8 + hi * 4] = w4;
            }
        lML[item][0][l31] = m_r;
        lML[item][1][l31] = l_r;
    }
    __syncthreads();
    if (half == 1) {
        float m0 = lML[item][0][l31];
        float l0v = lML[item][1][l31];
        float M = fmaxf(m0, m_r);
        float a0 = __expf(m0 - M);
        float a1 = __expf(m_r - M);
        float linv = 1.0f / (l0v * a0 + l_r * a1);
        size_t base = ((size_t)b * S_LEN + qrow) * DM + h * DH;
        #pragma unroll
        for (int dc = 0; dc < 2; dc++)
            #pragma unroll
            for (int g2 = 0; g2 < 4; g2++) {
                f32x4 part = *(const f32x4*)&lO[item][l31][dc * 32 + g2 * 8 + hi * 4];
                s16x4 outv;
                #pragma unroll
                for (int rr = 0; rr < 4; rr++)
                    outv[rr] = f2bf((part[rr] * a0 + (dc ? o1 : o0)[g2 * 4 + rr] * a1) * linv);
                *(s16x4*)(Oo + base + dc * 32 + g2 * 8 + hi * 4) = outv;
            }
    }
}

extern "C" void kernel_launch(void* const* d_in, const int* in_sizes, int n_in,
                              void* d_out, int out_size, void* d_ws, size_t ws_size,
                              hipStream_t stream) {
    const float* x  = (const float*)d_in[0];
    const float* wq = (const float*)d_in[1];
    const float* wk = (const float*)d_in[2];
    const float* wv = (const float*)d_in[3];
    const float* wo = (const float*)d_in[4];
    float* out = (float*)d_out;

    short* ws = (short*)d_ws;
    size_t off = 0;
    short* xb  = ws + off; off += (size_t)BS * DM;
    short* wqb = ws + off; off += (size_t)DM * DM;
    short* wkb = ws + off; off += (size_t)DM * DM;
    short* wvb = ws + off; off += (size_t)DM * DM;
    short* wob = ws + off; off += (size_t)DM * DM;
    short* Qb  = ws + off; off += (size_t)BS * DM;
    short* Kb  = ws + off; off += (size_t)BS * DM;
    short* Vtb = ws + off; off += (size_t)BS * DM;
    short* attn_o = xb;  // reuse: x dead after projections

    {
        int n4 = (BS * DM) / 4;
        cast_kernel<<<n4 / 256, 256, 0, stream>>>(x, xb, n4);
        int w4 = (DM * DM) / 4;
        cast_kernel<<<w4 / 256, 256, 0, stream>>>(wq, wqb, w4);
        cast_kernel<<<w4 / 256, 256, 0, stream>>>(wk, wkb, w4);
        cast_kernel<<<w4 / 256, 256, 0, stream>>>(wv, wvb, w4);
        cast_kernel<<<w4 / 256, 256, 0, stream>>>(wo, wob, w4);
    }

    dim3 pgrid(BS / 128, DM / 128);
    gemm_bt<1><<<pgrid, 256, 0, stream>>>(xb, wqb, Qb,  BS, DM, DM);
    gemm_bt<1><<<pgrid, 256, 0, stream>>>(xb, wkb, Kb,  BS, DM, DM);
    gemm_bt<2><<<pgrid, 256, 0, stream>>>(xb, wvb, Vtb, BS, DM, DM);

    attn_split_kernel<<<dim3(2048), 256, 0, stream>>>(Qb, Kb, Vtb, attn_o);

    gemm_bt<0><<<pgrid, 256, 0, stream>>>(attn_o, wob, out, BS, DM, DM);
}